// Round 5
// baseline (127.577 us; speedup 1.0000x reference)
//
#include <hip/hip_runtime.h>
#include <hip/hip_bf16.h>

// Sizes (fixed by the problem)
#define VOCAB 50257
#define EMB   1024
#define HID   1024
#define OUTV  50257

// All float tensors are float32 on device (confirmed round 2: passed with
// absmax 2e-3). Byte floor: Wdec 206MB + Wx/Wh 33.5MB + misc ~= 240MB
// @ ~7TB/s = ~34.3us.
//
// Round 4: hipLaunchCooperativeKernel silently no-opped (output never
// written). This round: same single-dispatch schedule on a PLAIN launch with
// a manual device-scope arrival barrier. Safe because grid==1024 blocks at
// __launch_bounds__(256,4) -> 4 blocks/CU x 256 CUs: all blocks co-resident.
// Barrier counter in ws, zeroed each call via hipMemsetAsync (ws is poisoned
// 0xAA once and never re-poisoned). Failsafe spin cap turns a co-residency
// violation into a wrong answer instead of a hang.

__device__ __forceinline__ float wave_reduce(float v) {
    #pragma unroll
    for (int off = 32; off > 0; off >>= 1) v += __shfl_xor(v, off);
    return v;
}

__device__ __forceinline__ float dot4(float4 a, float4 b) {
    return a.x * b.x + a.y * b.y + a.z * b.z + a.w * b.w;
}

__global__ __launch_bounds__(256, 4) void k_milstm_fused(
        const int* __restrict__ inp,
        const float* __restrict__ emb,
        const float* __restrict__ Wx, const float* __restrict__ bx,
        const float* __restrict__ Wh, const float* __restrict__ bh,
        const float* __restrict__ h0,
        const float* __restrict__ alpha, const float* __restrict__ beta1,
        const float* __restrict__ beta2,
        const float* __restrict__ c0,
        const float* __restrict__ Wdec, const float* __restrict__ bdec,
        float* __restrict__ out,
        float* __restrict__ hx_ws,
        unsigned* __restrict__ bar) {
    __shared__ float m_s[4];
    __shared__ float xs[HID];

    const int g    = threadIdx.x >> 6;              // wave in block: gate 0..3
    const int lane = threadIdx.x & 63;
    const int j    = blockIdx.x;                    // hidden unit (grid == 1024)
    const int r    = g * HID + j;                   // gate row in [0,4096)

    // ---- Phase A: gates + cell (block j owns hidden unit j) ----
    {
        const size_t x_off = (size_t)inp[0] * (size_t)EMB;
        const float* wx_row = Wx + (size_t)r * EMB;
        const float* wh_row = Wh + (size_t)r * HID;

        float accx = 0.f, acch = 0.f;
        #pragma unroll
        for (int s = 0; s < 4; ++s) {
            const int c = s * 256 + lane * 4;       // 4 floats (16B) per lane
            float4 wxv = *(const float4*)(wx_row + c);
            float4 xv  = *(const float4*)(emb + x_off + c);
            float4 whv = *(const float4*)(wh_row + c);
            float4 hv  = *(const float4*)(h0 + c);
            accx += dot4(wxv, xv);
            acch += dot4(whv, hv);
        }
        accx = wave_reduce(accx);
        acch = wave_reduce(acch);

        if (lane == 0) {
            float gx = accx + bx[r];
            float gh = acch + bh[r];
            m_s[g] = alpha[r] * gx * gh + beta1[r] * gx + beta2[r] * gh;
        }
        __syncthreads();

        if (threadIdx.x == 0) {
            float fg = 1.f / (1.f + expf(-m_s[0]));
            float ig = 1.f / (1.f + expf(-m_s[1]));
            float og = 1.f / (1.f + expf(-m_s[2]));
            float zt = tanhf(m_s[3]);
            float c  = fg * c0[j] + ig * zt;
            float h  = og * tanhf(c);
            hx_ws[j]            = h;                // for phase B
            out[OUTV + j]       = h;                // hx output
            out[OUTV + HID + j] = c;                // cx output
        }
    }

    // ---- Grid barrier (all 1024 blocks co-resident by construction) ----
    // thread 0 wrote hx_ws[j]; same thread releases + arrives.
    if (threadIdx.x == 0) {
        __threadfence();                            // release hx_ws write
        atomicAdd(bar, 1u);                         // device-scope
        unsigned spins = 0;
        while (__hip_atomic_load(bar, __ATOMIC_RELAXED,
                                 __HIP_MEMORY_SCOPE_AGENT) < 1024u) {
            if (++spins > 100000000u) break;        // failsafe: fail, don't hang
        }
        __threadfence();                            // acquire hx_ws writes
    }
    __syncthreads();

    // ---- Phase B: decoder (persistent grid-stride over rows) ----
    for (int t = threadIdx.x; t < HID; t += 256) xs[t] = hx_ws[t];
    __syncthreads();

    const int wave_gid = blockIdx.x * 4 + g;        // 0..4095
    for (int row = wave_gid; row < OUTV; row += 4096) {
        const float* wrow = Wdec + (size_t)row * HID;
        float acc = 0.f;
        #pragma unroll
        for (int s = 0; s < 4; ++s) {
            const int c = s * 256 + lane * 4;
            float4 w = *(const float4*)(wrow + c);
            float4 x = *(const float4*)(xs + c);
            acc += dot4(w, x);
        }
        acc = wave_reduce(acc);
        if (lane == 0) out[row] = acc + bdec[row];
    }
}

extern "C" void kernel_launch(void* const* d_in, const int* in_sizes, int n_in,
                              void* d_out, int out_size, void* d_ws, size_t ws_size,
                              hipStream_t stream) {
    const int*   inp   = (const int*)d_in[0];
    const float* h0    = (const float*)d_in[1];
    const float* c0    = (const float*)d_in[2];
    const float* emb   = (const float*)d_in[3];
    const float* Wx    = (const float*)d_in[4];
    const float* bx    = (const float*)d_in[5];
    const float* Wh    = (const float*)d_in[6];
    const float* bh    = (const float*)d_in[7];
    const float* alpha = (const float*)d_in[8];
    const float* beta1 = (const float*)d_in[9];
    const float* beta2 = (const float*)d_in[10];
    const float* Wdec  = (const float*)d_in[11];
    const float* bdec  = (const float*)d_in[12];

    float* out   = (float*)d_out;              // [0,50257): out, then hx[1024], cx[1024]
    float*    hx_ws = (float*)d_ws;            // 1024 f32
    unsigned* bar   = (unsigned*)((char*)d_ws + 4096);  // 1 u32, zeroed each call

    hipMemsetAsync(bar, 0, sizeof(unsigned), stream);

    k_milstm_fused<<<1024, 256, 0, stream>>>(inp, emb, Wx, bx, Wh, bh, h0,
                                             alpha, beta1, beta2, c0,
                                             Wdec, bdec, out, hx_ws, bar);
}

// Round 6
// 45.653 us; speedup vs baseline: 2.7945x; 2.7945x over previous
//
#include <hip/hip_runtime.h>
#include <hip/hip_bf16.h>

// Sizes (fixed by the problem)
#define VOCAB 50257
#define EMB   1024
#define HID   1024
#define OUTV  50257

// All float tensors are float32 on device (confirmed round 2).
//
// History: R3 two-kernel = 42.9us. R5 fused + spin barrier = 180us/dispatch:
// barrier contention collapse (1024 AGENT-scope spinners on one line, which
// must bypass the non-coherent per-XCD L2s and serialize at the die-level
// coherence point). Fusion retired. Also learned: timed replays are L3-warm
// (FETCH~0; Wdec+Wx/Wh = 240MB < 256MiB L3), so the ceiling is the L3 read
// path, not HBM.
//
// This round: persistent-grid decoder (2048 blocks, hx staged in LDS once
// per block, 8192 waves, 2-row interleave for 8 outstanding loads/wave).

__device__ __forceinline__ float wave_reduce(float v) {
    #pragma unroll
    for (int off = 32; off > 0; off >>= 1) v += __shfl_xor(v, off);
    return v;
}

__device__ __forceinline__ float dot4(float4 a, float4 b) {
    return a.x * b.x + a.y * b.y + a.z * b.z + a.w * b.w;
}

// Kernel 1 (fused gates + cell): block j = hidden unit j (1024 blocks).
// Wave g computes gate row r = g*HID + j; thread 0 finishes the cell math.
__global__ __launch_bounds__(256) void k_gates_cell(
        const int* __restrict__ inp,
        const float* __restrict__ emb,
        const float* __restrict__ Wx, const float* __restrict__ bx,
        const float* __restrict__ Wh, const float* __restrict__ bh,
        const float* __restrict__ h0,
        const float* __restrict__ alpha, const float* __restrict__ beta1,
        const float* __restrict__ beta2,
        const float* __restrict__ c0,
        float* __restrict__ hx_ws,
        float* __restrict__ out_hx, float* __restrict__ out_cx) {
    __shared__ float m_s[4];

    const int g    = threadIdx.x >> 6;              // gate 0..3 (f,i,o,z)
    const int lane = threadIdx.x & 63;
    const int j    = blockIdx.x;                    // hidden unit
    const int r    = g * HID + j;                   // gate row in [0,4096)

    const size_t x_off = (size_t)inp[0] * (size_t)EMB;
    const float* wx_row = Wx + (size_t)r * EMB;
    const float* wh_row = Wh + (size_t)r * HID;

    float accx = 0.f, acch = 0.f;
    #pragma unroll
    for (int s = 0; s < 4; ++s) {
        const int c = s * 256 + lane * 4;           // 4 floats (16B) per lane
        float4 wxv = *(const float4*)(wx_row + c);
        float4 xv  = *(const float4*)(emb + x_off + c);
        float4 whv = *(const float4*)(wh_row + c);
        float4 hv  = *(const float4*)(h0 + c);
        accx += dot4(wxv, xv);
        acch += dot4(whv, hv);
    }
    accx = wave_reduce(accx);
    acch = wave_reduce(acch);

    if (lane == 0) {
        float gx = accx + bx[r];
        float gh = acch + bh[r];
        m_s[g] = alpha[r] * gx * gh + beta1[r] * gx + beta2[r] * gh;
    }
    __syncthreads();

    if (threadIdx.x == 0) {
        float fg = 1.f / (1.f + expf(-m_s[0]));
        float ig = 1.f / (1.f + expf(-m_s[1]));
        float og = 1.f / (1.f + expf(-m_s[2]));
        float zt = tanhf(m_s[3]);
        float c  = fg * c0[j] + ig * zt;
        float h  = og * tanhf(c);
        hx_ws[j]  = h;
        out_hx[j] = h;
        out_cx[j] = c;
    }
}

// Kernel 2: persistent decoder. 2048 blocks x 4 waves = 8192 waves; each wave
// owns rows {wave_gid + 16384k} and {wave_gid + 8192 + 16384k} (2-row
// interleave -> 8 outstanding float4 loads). hx staged in LDS once per block.
#define NWAVE 8192
__global__ __launch_bounds__(256) void k_dec(
        const float* __restrict__ hx_ws,
        const float* __restrict__ Wdec, const float* __restrict__ bdec,
        float* __restrict__ out) {
    __shared__ float xs[HID];
    for (int t = threadIdx.x; t < HID; t += 256) xs[t] = hx_ws[t];
    __syncthreads();

    const int g    = threadIdx.x >> 6;
    const int lane = threadIdx.x & 63;
    const int wave_gid = blockIdx.x * 4 + g;        // 0..8191

    for (int row = wave_gid; row < OUTV; row += 2 * NWAVE) {
        const int rowB = row + NWAVE;
        const float* wA = Wdec + (size_t)row * HID;
        float accA = 0.f, accB = 0.f;
        if (rowB < OUTV) {
            const float* wB = Wdec + (size_t)rowB * HID;
            #pragma unroll
            for (int s = 0; s < 4; ++s) {
                const int c = s * 256 + lane * 4;
                float4 a = *(const float4*)(wA + c);
                float4 b = *(const float4*)(wB + c);
                float4 x = *(const float4*)(xs + c);
                accA += dot4(a, x);
                accB += dot4(b, x);
            }
            accB = wave_reduce(accB);
        } else {
            #pragma unroll
            for (int s = 0; s < 4; ++s) {
                const int c = s * 256 + lane * 4;
                float4 a = *(const float4*)(wA + c);
                float4 x = *(const float4*)(xs + c);
                accA += dot4(a, x);
            }
        }
        accA = wave_reduce(accA);
        if (lane == 0) {
            out[row] = accA + bdec[row];
            if (rowB < OUTV) out[rowB] = accB + bdec[rowB];
        }
    }
}

extern "C" void kernel_launch(void* const* d_in, const int* in_sizes, int n_in,
                              void* d_out, int out_size, void* d_ws, size_t ws_size,
                              hipStream_t stream) {
    const int*   inp   = (const int*)d_in[0];
    const float* h0    = (const float*)d_in[1];
    const float* c0    = (const float*)d_in[2];
    const float* emb   = (const float*)d_in[3];
    const float* Wx    = (const float*)d_in[4];
    const float* bx    = (const float*)d_in[5];
    const float* Wh    = (const float*)d_in[6];
    const float* bh    = (const float*)d_in[7];
    const float* alpha = (const float*)d_in[8];
    const float* beta1 = (const float*)d_in[9];
    const float* beta2 = (const float*)d_in[10];
    const float* Wdec  = (const float*)d_in[11];
    const float* bdec  = (const float*)d_in[12];

    float* out   = (float*)d_out;              // [0,50257): out, then hx[1024], cx[1024]
    float* hx_ws = (float*)d_ws;               // 1024 f32

    k_gates_cell<<<1024, 256, 0, stream>>>(inp, emb, Wx, bx, Wh, bh, h0,
                                           alpha, beta1, beta2, c0,
                                           hx_ws, out + OUTV, out + OUTV + HID);
    k_dec<<<2048, 256, 0, stream>>>(hx_ws, Wdec, bdec, out);
}

// Round 7
// 42.284 us; speedup vs baseline: 3.0172x; 1.0797x over previous
//
#include <hip/hip_runtime.h>
#include <hip/hip_bf16.h>

// Sizes (fixed by the problem)
#define VOCAB 50257
#define EMB   1024
#define HID   1024
#define OUTV  50257

// All float tensors are float32 on device (confirmed round 2).
//
// History: R3 two-kernel = 42.9us. R5 fused + tight spin barrier = 180us
// (coherence-point poll storm; barrier correct but slow). R6 persistent
// decoder w/ 32MB-apart row pairs = 45.7us (regression: distant dual streams
// + persistent tail). Replays are L3-warm (FETCH~0) yet stream at ~7TB/s ->
// per-XCD L2-fill path is the cap. Floor ~= 240MB/7TB/s = 34.3us + launches.
//
// This round: R3 contiguous mapping, decoder with NO LDS/no syncthreads
// (per-lane hx slice lives in 4 float4 registers, L1-hit), adjacent-pair
// row interleave (8 outstanding loads/wave, rows 4KB apart).

__device__ __forceinline__ float wave_reduce(float v) {
    #pragma unroll
    for (int off = 32; off > 0; off >>= 1) v += __shfl_xor(v, off);
    return v;
}

__device__ __forceinline__ float dot4(float4 a, float4 b) {
    return a.x * b.x + a.y * b.y + a.z * b.z + a.w * b.w;
}

// Kernel 1 (gates + cell): block j = hidden unit j (1024 blocks).
// Wave g computes gate row r = g*HID + j; thread 0 finishes the cell math.
__global__ __launch_bounds__(256) void k_gates_cell(
        const int* __restrict__ inp,
        const float* __restrict__ emb,
        const float* __restrict__ Wx, const float* __restrict__ bx,
        const float* __restrict__ Wh, const float* __restrict__ bh,
        const float* __restrict__ h0,
        const float* __restrict__ alpha, const float* __restrict__ beta1,
        const float* __restrict__ beta2,
        const float* __restrict__ c0,
        float* __restrict__ hx_ws,
        float* __restrict__ out_hx, float* __restrict__ out_cx) {
    __shared__ float m_s[4];

    const int g    = threadIdx.x >> 6;              // gate 0..3 (f,i,o,z)
    const int lane = threadIdx.x & 63;
    const int j    = blockIdx.x;                    // hidden unit
    const int r    = g * HID + j;                   // gate row in [0,4096)

    const size_t x_off = (size_t)inp[0] * (size_t)EMB;
    const float* wx_row = Wx + (size_t)r * EMB;
    const float* wh_row = Wh + (size_t)r * HID;

    float accx = 0.f, acch = 0.f;
    #pragma unroll
    for (int s = 0; s < 4; ++s) {
        const int c = s * 256 + lane * 4;           // 4 floats (16B) per lane
        float4 wxv = *(const float4*)(wx_row + c);
        float4 xv  = *(const float4*)(emb + x_off + c);
        float4 whv = *(const float4*)(wh_row + c);
        float4 hv  = *(const float4*)(h0 + c);
        accx += dot4(wxv, xv);
        acch += dot4(whv, hv);
    }
    accx = wave_reduce(accx);
    acch = wave_reduce(acch);

    if (lane == 0) {
        float gx = accx + bx[r];
        float gh = acch + bh[r];
        m_s[g] = alpha[r] * gx * gh + beta1[r] * gx + beta2[r] * gh;
    }
    __syncthreads();

    if (threadIdx.x == 0) {
        float fg = 1.f / (1.f + expf(-m_s[0]));
        float ig = 1.f / (1.f + expf(-m_s[1]));
        float og = 1.f / (1.f + expf(-m_s[2]));
        float zt = tanhf(m_s[3]);
        float c  = fg * c0[j] + ig * zt;
        float h  = og * tanhf(c);
        hx_ws[j]  = h;
        out_hx[j] = h;
        out_cx[j] = c;
    }
}

// Kernel 2: decoder. Block b covers rows [8b, 8b+8); wave g handles the
// ADJACENT pair rows 8b+2g, 8b+2g+1 (4KB apart -> one locality stream,
// 8 outstanding 16B loads). Per-lane hx slice in registers; no LDS, no sync.
__global__ __launch_bounds__(256) void k_dec(
        const float* __restrict__ hx_ws,
        const float* __restrict__ Wdec, const float* __restrict__ bdec,
        float* __restrict__ out) {
    const int g    = threadIdx.x >> 6;
    const int lane = threadIdx.x & 63;
    const int c0   = lane * 4;

    // per-lane hx slice: columns c0 + {0,256,512,768} (+0..3). L1-hit.
    float4 x0 = *(const float4*)(hx_ws + c0);
    float4 x1 = *(const float4*)(hx_ws + 256 + c0);
    float4 x2 = *(const float4*)(hx_ws + 512 + c0);
    float4 x3 = *(const float4*)(hx_ws + 768 + c0);

    const int rowA = blockIdx.x * 8 + g * 2;
    const int rowB = rowA + 1;
    if (rowA >= OUTV) return;

    const float* wA = Wdec + (size_t)rowA * HID;
    if (rowB < OUTV) {
        const float* wB = Wdec + (size_t)rowB * HID;
        float4 a0 = *(const float4*)(wA + c0);
        float4 a1 = *(const float4*)(wA + 256 + c0);
        float4 a2 = *(const float4*)(wA + 512 + c0);
        float4 a3 = *(const float4*)(wA + 768 + c0);
        float4 b0 = *(const float4*)(wB + c0);
        float4 b1 = *(const float4*)(wB + 256 + c0);
        float4 b2 = *(const float4*)(wB + 512 + c0);
        float4 b3 = *(const float4*)(wB + 768 + c0);
        float accA = dot4(a0, x0) + dot4(a1, x1) + dot4(a2, x2) + dot4(a3, x3);
        float accB = dot4(b0, x0) + dot4(b1, x1) + dot4(b2, x2) + dot4(b3, x3);
        accA = wave_reduce(accA);
        accB = wave_reduce(accB);
        if (lane == 0) {
            out[rowA] = accA + bdec[rowA];
            out[rowB] = accB + bdec[rowB];
        }
    } else {
        float4 a0 = *(const float4*)(wA + c0);
        float4 a1 = *(const float4*)(wA + 256 + c0);
        float4 a2 = *(const float4*)(wA + 512 + c0);
        float4 a3 = *(const float4*)(wA + 768 + c0);
        float accA = dot4(a0, x0) + dot4(a1, x1) + dot4(a2, x2) + dot4(a3, x3);
        accA = wave_reduce(accA);
        if (lane == 0) out[rowA] = accA + bdec[rowA];
    }
}

extern "C" void kernel_launch(void* const* d_in, const int* in_sizes, int n_in,
                              void* d_out, int out_size, void* d_ws, size_t ws_size,
                              hipStream_t stream) {
    const int*   inp   = (const int*)d_in[0];
    const float* h0    = (const float*)d_in[1];
    const float* c0    = (const float*)d_in[2];
    const float* emb   = (const float*)d_in[3];
    const float* Wx    = (const float*)d_in[4];
    const float* bx    = (const float*)d_in[5];
    const float* Wh    = (const float*)d_in[6];
    const float* bh    = (const float*)d_in[7];
    const float* alpha = (const float*)d_in[8];
    const float* beta1 = (const float*)d_in[9];
    const float* beta2 = (const float*)d_in[10];
    const float* Wdec  = (const float*)d_in[11];
    const float* bdec  = (const float*)d_in[12];

    float* out   = (float*)d_out;              // [0,50257): out, then hx[1024], cx[1024]
    float* hx_ws = (float*)d_ws;               // 1024 f32

    k_gates_cell<<<1024, 256, 0, stream>>>(inp, emb, Wx, bx, Wh, bh, h0,
                                           alpha, beta1, beta2, c0,
                                           hx_ws, out + OUTV, out + OUTV + HID);
    k_dec<<<(OUTV + 7) / 8, 256, 0, stream>>>(hx_ws, Wdec, bdec, out);
}